// Round 6
// baseline (830.704 us; speedup 1.0000x reference)
//
#include <hip/hip_runtime.h>
#include <hip/hip_bf16.h>

using bf16 = __hip_bfloat16;
typedef unsigned short u16;
typedef __attribute__((ext_vector_type(8))) short short8;
typedef __attribute__((ext_vector_type(4))) float f32x4;

#define DEVFN __device__ __forceinline__

DEVFN u16 f2bu(float v) { return __builtin_bit_cast(u16, __float2bfloat16(v)); }
DEVFN float us2f(u16 u) { union { unsigned int i; float f; } x; x.i = ((unsigned int)u) << 16; return x.f; }
DEVFN void unp8(uint4 u, float* f) {
  f[0]=us2f(u.x & 0xffffu); f[1]=us2f(u.x >> 16);
  f[2]=us2f(u.y & 0xffffu); f[3]=us2f(u.y >> 16);
  f[4]=us2f(u.z & 0xffffu); f[5]=us2f(u.z >> 16);
  f[6]=us2f(u.w & 0xffffu); f[7]=us2f(u.w >> 16);
}

DEVFN f32x4 mfma16(short8 a, short8 b, f32x4 c) {
  return __builtin_amdgcn_mfma_f32_16x16x32_bf16(a, b, c, 0, 0, 0);
}

// async global->LDS, 16B per lane; LDS dest = wave-uniform base + lane*16
DEVFN void gl16(const u16* g, u16* l) {
  __builtin_amdgcn_global_load_lds((const __attribute__((address_space(1))) void*)g,
                                   (__attribute__((address_space(3))) void*)l, 16, 0, 0);
}

// fast exact-GELU: erf via Abramowitz-Stegun 7.1.26 (|eps|<=1.5e-7), branch-free.
DEVFN float gelu_f(float v) {
  float z = v * 0.70710678118654752f;
  float a = __builtin_fabsf(z);
  float t = __builtin_amdgcn_rcpf(__builtin_fmaf(0.3275911f, a, 1.0f));
  float q = __builtin_fmaf(t, 1.061405429f, -1.453152027f);
  q = __builtin_fmaf(t, q, 1.421413741f);
  q = __builtin_fmaf(t, q, -0.284496736f);
  q = __builtin_fmaf(t, q, 0.254829592f);
  float e = __expf(-z * z);
  float y = __builtin_fmaf(-q * t, e, 1.0f);   // erf(|z|)
  float er = __builtin_copysignf(y, z);
  return 0.5f * v * (1.0f + er);
}

// T1 CHUNKED XCD swizzle (HK chiplet_transform_chunked): a chunk = the
// gridDim.x n-sibling blocks of one (m[,e]) tile -> same XCD (A-panel L2
// locality); chunks round-robin across the 8 XCDs -> per-XCD load is
// ~total/8 from EVERY expert (fixes the expert-per-XCD imbalance of the
// contiguous m204 form). Bijective iff (nwg/8) % gridDim.x == 0
// (mg1: 1024/16, mg2: 256/4, bgemm: 32/4 — all integer).
DEVFN void xcd_swz(int& bx, int& by, int& bz) {
  const int nx = gridDim.x, ny = gridDim.y;
  const int orig = blockIdx.x + nx * (blockIdx.y + ny * blockIdx.z);
  const int x = orig & 7, k = orig >> 3;
  const int kc = k / nx, kp = k - kc * nx;
  const int c = x + 8 * kc;          // chunk id in [0, nwg/nx)
  bx = kp;
  by = c % ny;
  bz = c / ny;
}

// ---------------- workspace layout (float element offsets) ----------------
static constexpr size_t OF_PATCH = 0;          // XP bf16 [8192,640] = 2,621,440 fl ; later XNB bf16 + YB f32
static constexpr size_t OF_E     = 4816896;    // ebuf f32 [8192,512]
static constexpr size_t OF_XN    = 9011200;    // xn f32 [8192,512]
static constexpr size_t OF_Q     = 13205504;
static constexpr size_t OF_FV    = 38371328;   // 32*512
static constexpr size_t OF_GATES = 38387712;   // 8192*2
static constexpr size_t OF_IMPS  = 38404096;   // 8 f32 (memset with CNT: 64B)
static constexpr size_t OF_CNT   = 38404104;   // 8 i32
static constexpr size_t OF_BASE  = 38404112;   // 8 i32
static constexpr size_t OF_CURS  = 38404120;   // 8 i32
static constexpr size_t OF_LOSS  = 38404128;   // 1 f32 (+pad)
static constexpr size_t OF_TOPI  = 38404136;   // 8192*2 i32
static constexpr size_t OF_RPOS  = 38420520;   // 8192*2 i32
static constexpr size_t OF_RLIST = 38436904;   // 16384 i32
// Pre-MoE sublayout of [OF_Q, OF_O1):
static constexpr size_t OF_Q16   = 13205504;   // bf16 [8192,512]
static constexpr size_t OF_K16   = 15302656;
static constexpr size_t OF_VT    = 17399808;   // bf16 [32,8,64,256]
static constexpr size_t OF_CTX16 = 19496960;   // bf16 [8192,512]
static constexpr size_t OF_PET   = 21594112;   // bf16 [512,640]
static constexpr size_t OF_WQT   = 21757952;   // bf16 [512,512] each
static constexpr size_t OF_WKT   = 21889024;
static constexpr size_t OF_WVT   = 22020096;
static constexpr size_t OF_WOT   = 22151168;   // ends 22282240 < OF_O1
static constexpr size_t OF_O1    = 29982720;   // o1 f32 ; earlier Pg bf16 spans O1..FV ; W1T overlay
static constexpr size_t OF_O2    = 34177024;   // o2 f32 ; W2T overlay
// MoE overlays: H (bf16 16384x2048) on [OF_Q, OF_O1); YB f32 on [0, 8388608); XNB bf16 on [0, 2097152)

// ---------------- patchify: x[B,3,224,224] -> XP bf16 [8192,640] (zero-pad 588..639) ----------------
__global__ __launch_bounds__(256) void k_patchify(const float* __restrict__ x, u16* __restrict__ XP) {
  int idx = blockIdx.x * 256 + threadIdx.x;
  if (idx >= 8192 * 640) return;
  int row = idx / 640, j = idx - row * 640;
  u16 v = 0;
  if (j < 588) {
    int b = row >> 8, s = row & 255;
    int hh = s >> 4, ww = s & 15;
    int c = j % 3, tt = j / 3;
    int p2 = tt % 14, p1 = tt / 14;
    int src = ((b * 3 + c) * 224 + hh * 14 + p1) * 224 + (ww * 14 + p2);
    v = f2bu(x[src]);
  }
  XP[idx] = v;
}

// ---------------- dense weight cvt+transpose: W[K,512] f32 -> WT[512,KP] bf16 ----------------
__global__ __launch_bounds__(256) void k_wcvtd(const float* __restrict__ W, u16* __restrict__ WT, int K, int KP)
{
  __shared__ float s[32][33];
  const int t = threadIdx.x;
  const int tx = t & 31, ty = t >> 5;
  const int k0 = blockIdx.x * 32, n0 = blockIdx.y * 32;
#pragma unroll
  for (int i = 0; i < 4; i++) {
    int kk = k0 + ty + i * 8;
    s[ty + i * 8][tx] = (kk < K) ? W[(size_t)kk * 512 + n0 + tx] : 0.f;
  }
  __syncthreads();
#pragma unroll
  for (int i = 0; i < 4; i++) WT[(size_t)(n0 + ty + i * 8) * KP + k0 + tx] = f2bu(s[tx][ty + i * 8]);
}

// ---------------- MoE weight cvt+transpose (per expert): W[K,N] f32 -> Wt[N,K] bf16 ----------------
__global__ __launch_bounds__(256) void k_wcvt(const float* __restrict__ W, u16* __restrict__ Wt, int K, int N)
{
  __shared__ float s[32][33];
  const int t = threadIdx.x;
  const int tx = t & 31, ty = t >> 5;
  const int k0 = blockIdx.x * 32, n0 = blockIdx.y * 32;
  const size_t es = (size_t)K * N;
  const float* We = W + (size_t)blockIdx.z * es;
  u16* Wte = Wt + (size_t)blockIdx.z * es;
#pragma unroll
  for (int i = 0; i < 4; i++) s[ty + i * 8][tx] = We[(size_t)(k0 + ty + i * 8) * N + n0 + tx];
  __syncthreads();
#pragma unroll
  for (int i = 0; i < 4; i++) Wte[(size_t)(n0 + ty + i * 8) * K + k0 + tx] = f2bu(s[tx][ty + i * 8]);
}

// ======== shared MFMA engine pieces ========
// Catalog-minimum 2-phase (T3 recipe): per K-step
//   { stage(t+1 -> other buf); ds_read+MFMA(t); vmcnt(0); barrier }
#define WAIT_VM0  asm volatile("s_waitcnt vmcnt(0)" ::: "memory")
#define BARRIER   __builtin_amdgcn_s_barrier()

DEVFN void mma_stage(const u16* const agp[4], const u16* const bgp[4],
                     u16* Asb, u16* Bsb, int k0, int widx)
{
#pragma unroll
  for (int q = 0; q < 4; q++) {
    gl16(agp[q] + k0, Asb + (q * 256 + widx * 64) * 8);
    gl16(bgp[q] + k0, Bsb + (q * 256 + widx * 64) * 8);
  }
}

DEVFN void mma_step(f32x4 acc[4][4], const u16* As, const u16* Bs,
                    int wm, int wn, int ml, int kq)
{
  __builtin_amdgcn_s_setprio(1);   // T5: favor compute-phase waves
#pragma unroll
  for (int ks = 0; ks < 2; ks++) {
    const int c = ks * 4 + kq;
    short8 af[4], bf[4];
#pragma unroll
    for (int i = 0; i < 4; i++) {
      const int row = wm + i * 16 + ml;
      af[i] = *(const short8*)&As[row * 64 + ((c ^ (row & 7)) << 3)];
    }
#pragma unroll
    for (int j = 0; j < 4; j++) {
      const int row = wn + j * 16 + ml;
      bf[j] = *(const short8*)&Bs[row * 64 + ((c ^ (row & 7)) << 3)];
    }
#pragma unroll
    for (int i = 0; i < 4; i++)
#pragma unroll
      for (int j = 0; j < 4; j++) acc[i][j] = mfma16(af[i], bf[j], acc[i][j]);
  }
  __builtin_amdgcn_s_setprio(0);
}

DEVFN void mma_loop(f32x4 acc[4][4], const u16* const agp[4], const u16* const bgp[4],
                    u16* SB, int K, int wm, int wn, int ml, int kq, int widx)
{
  const int NT = K >> 6;                       // 8 / 10 / 32 for our callers
  mma_stage(agp, bgp, SB, SB + 8192, 0, widx); // tile 0 -> buf0
  WAIT_VM0;
  BARRIER;                                     // tile 0 resident for all waves
  int cur = 0;
  for (int t = 0; t + 1 < NT; ++t) {
    u16* Nx = SB + ((cur ^ 1) << 14);
    mma_stage(agp, bgp, Nx, Nx + 8192, (t + 1) << 6, widx);  // stage t+1
    u16* Cu = SB + (cur << 14);
    mma_step(acc, Cu, Cu + 8192, wm, wn, ml, kq);            // compute t
    WAIT_VM0;                                                 // t+1 landed
    BARRIER;                                                  // all reads(t) done
    cur ^= 1;
  }
  u16* Cu = SB + (cur << 14);
  mma_step(acc, Cu, Cu + 8192, wm, wn, ml, kq);               // last tile
}

// Wave-private accumulator transpose through LDS. ep points at this wave's own
// 16x68 float region; within-wave RAW ordering is enforced by lgkmcnt the
// compiler inserts — NO block barrier needed.
DEVFN void ep_xpose(float* ep, const f32x4* ai, int kq, int ml, int er, int ec, float* v)
{
#pragma unroll
  for (int j = 0; j < 4; j++)
#pragma unroll
    for (int r = 0; r < 4; r++)
      ep[(kq * 4 + r) * 68 + j * 16 + ml] = ai[j][r];
#pragma unroll
  for (int u = 0; u < 4; u++) {
    float4 f = *(const float4*)&ep[er * 68 + ec + u * 4];
    v[u * 4 + 0] = f.x; v[u * 4 + 1] = f.y; v[u * 4 + 2] = f.z; v[u * 4 + 3] = f.w;
  }
}

// ---------------- dense MFMA GEMM ----------------
template<int MODE>
__global__ __launch_bounds__(256) void k_bgemm(const u16* __restrict__ A, const u16* __restrict__ BT,
    const float* __restrict__ bias, float* __restrict__ Cf, u16* __restrict__ O16,
    const float* __restrict__ pos, int K)
{
  int bx, by, bz; xcd_swz(bx, by, bz);
  const int m0 = by * 128, n0 = bx * 128;
  __shared__ alignas(16) u16 SB[32768];
  const int t = threadIdx.x;
  const int widx = t >> 6, lane = t & 63;
  const int wm = (widx & 1) * 64, wn = (widx >> 1) * 64;
  const int ml = lane & 15, kq = lane >> 4;
  const u16* agp[4]; const u16* bgp[4];
#pragma unroll
  for (int q = 0; q < 4; q++) {
    const int slot = q * 256 + t;
    const int row = slot >> 3;
    const int c = (slot & 7) ^ (row & 7);
    agp[q] = A + (size_t)(m0 + row) * K + c * 8;
    bgp[q] = BT + (size_t)(n0 + row) * K + c * 8;
  }
  f32x4 acc[4][4];
#pragma unroll
  for (int i = 0; i < 4; i++)
#pragma unroll
    for (int j = 0; j < 4; j++) acc[i][j] = (f32x4){0.f, 0.f, 0.f, 0.f};
  mma_loop(acc, agp, bgp, SB, K, wm, wn, ml, kq, widx);

  if (MODE == 3) {
#pragma unroll
    for (int j = 0; j < 4; j++) {
      const int n = n0 + wn + j * 16 + ml;
      const float bv = bias[n];
      const int h = n >> 6, d = n & 63;
#pragma unroll
      for (int i = 0; i < 4; i++) {
        const int mb = m0 + wm + i * 16 + kq * 4;
        const int b = mb >> 8, s0 = mb & 255;
        ushort4 w4;
        w4.x = f2bu(acc[i][j][0] + bv); w4.y = f2bu(acc[i][j][1] + bv);
        w4.z = f2bu(acc[i][j][2] + bv); w4.w = f2bu(acc[i][j][3] + bv);
        *(ushort4*)(O16 + ((size_t)(b * 8 + h) * 64 + d) * 256 + s0) = w4;
      }
    }
    return;
  }

  __syncthreads();   // all waves past final buf reads; ep region reusable
  float* ep = (float*)SB + widx * (16 * 68);
  const int er = lane >> 2, ec = (lane & 3) * 16;
  const int gn = n0 + wn + ec;
  float bb[16];
#pragma unroll
  for (int u = 0; u < 4; u++) {
    float4 f = *(const float4*)(bias + gn + u * 4);
    bb[u*4]=f.x; bb[u*4+1]=f.y; bb[u*4+2]=f.z; bb[u*4+3]=f.w;
  }
#pragma unroll
  for (int i = 0; i < 4; i++) {
    float v[16];
    ep_xpose(ep, acc[i], kq, ml, er, ec, v);
    const int gm = m0 + wm + i * 16 + er;
    if (MODE == 0) {
      const float* pr = pos + (size_t)(gm & 255) * 512 + gn;
      float* cp = Cf + (size_t)gm * 512 + gn;
#pragma unroll
      for (int u = 0; u < 4; u++) {
        float4 p = *(const float4*)(pr + u * 4);
        float4 o = {v[u*4]+bb[u*4]+p.x, v[u*4+1]+bb[u*4+1]+p.y, v[u*4+2]+bb[u*4+2]+p.z, v[u*4+3]+bb[u*4+3]+p.w};
        *(float4*)(cp + u * 4) = o;
      }
    } else if (MODE == 1) {
      union { u16 h[16]; uint4 q2[2]; } pk;
#pragma unroll
      for (int u = 0; u < 16; u++) pk.h[u] = f2bu(v[u] + bb[u]);
      u16* hp = O16 + (size_t)gm * 512 + gn;
      *(uint4*)hp = pk.q2[0]; *(uint4*)(hp + 8) = pk.q2[1];
    } else {  // MODE 2
      float* cp = Cf + (size_t)gm * 512 + gn;
#pragma unroll
      for (int u = 0; u < 4; u++) {
        float4 oldv = *(const float4*)(cp + u * 4);
        float4 o = {oldv.x+v[u*4]+bb[u*4], oldv.y+v[u*4+1]+bb[u*4+1], oldv.z+v[u*4+2]+bb[u*4+2], oldv.w+v[u*4+3]+bb[u*4+3]};
        *(float4*)(cp + u * 4) = o;
      }
    }
  }
}

// ---------------- LayerNorm over D=512 (writes f32 + bf16 copies) ----------------
__global__ __launch_bounds__(256) void k_ln(const float* __restrict__ X, float* __restrict__ Y,
    u16* __restrict__ YB16, const float* __restrict__ g, const float* __restrict__ b)
{
  __shared__ float red[256];
  const int row = blockIdx.x;
  const int t = threadIdx.x;
  const float* xr = X + (size_t)row * 512;
  float x0 = xr[t], x1 = xr[t + 256];
  red[t] = x0 + x1;
  __syncthreads();
  for (int s = 128; s > 0; s >>= 1) { if (t < s) red[t] += red[t + s]; __syncthreads(); }
  float mean = red[0] * (1.f / 512.f);
  __syncthreads();
  float d0 = x0 - mean, d1 = x1 - mean;
  red[t] = d0 * d0 + d1 * d1;
  __syncthreads();
  for (int s = 128; s > 0; s >>= 1) { if (t < s) red[t] += red[t + s]; __syncthreads(); }
  float rs = 1.f / sqrtf(red[0] * (1.f / 512.f) + 1e-5f);
  float y0 = d0 * rs * g[t]       + b[t];
  float y1 = d1 * rs * g[t + 256] + b[t + 256];
  float* yr = Y + (size_t)row * 512;
  yr[t] = y0; yr[t + 256] = y1;
  u16* br16 = YB16 + (size_t)row * 512;
  br16[t] = f2bu(y0); br16[t + 256] = f2bu(y1);
}

// ---------------- MFMA attention (unchanged) ----------------
__global__ __launch_bounds__(256) void k_fattn(const u16* __restrict__ Q16, const u16* __restrict__ K16,
    const u16* __restrict__ VT, u16* __restrict__ CTX16, u16* __restrict__ Pg)
{
  __shared__ u16 P[64 * 264];
  __shared__ u16 kv[64 * 136];
  const int t = threadIdx.x;
  const int qt = blockIdx.x, h = blockIdx.y, b = blockIdx.z;
  const int q0 = qt * 64;
  const int lane = t & 63, w = t >> 6;
  const int ml = lane & 15, kq = lane >> 4;
  const int srow = t >> 2, spart = t & 3;

  const size_t tokq = (size_t)(b * 256 + q0 + w * 16 + ml);
  short8 aq0 = *(const short8*)(Q16 + tokq * 512 + h * 64 + kq * 8);
  short8 aq1 = *(const short8*)(Q16 + tokq * 512 + h * 64 + 32 + kq * 8);

  f32x4 sacc[16];
#pragma unroll
  for (int i = 0; i < 16; i++) sacc[i] = (f32x4){0.f, 0.f, 0.f, 0.f};

  for (int kc = 0; kc < 4; kc++) {
    __syncthreads();
    {
      const u16* src = K16 + (size_t)(b * 256 + kc * 64 + srow) * 512 + h * 64 + spart * 16;
      uint4 v0 = *(const uint4*)src;
      uint4 v1 = *(const uint4*)(src + 8);
      *(uint4*)&kv[srow * 72 + spart * 16] = v0;
      *(uint4*)&kv[srow * 72 + spart * 16 + 8] = v1;
    }
    __syncthreads();
#pragma unroll
    for (int kt = 0; kt < 4; kt++) {
      short8 bk0 = *(const short8*)&kv[(kt * 16 + ml) * 72 + kq * 8];
      short8 bk1 = *(const short8*)&kv[(kt * 16 + ml) * 72 + 32 + kq * 8];
      sacc[kc * 4 + kt] = mfma16(aq0, bk0, sacc[kc * 4 + kt]);
      sacc[kc * 4 + kt] = mfma16(aq1, bk1, sacc[kc * 4 + kt]);
    }
  }

#pragma unroll
  for (int r = 0; r < 4; r++) {
    float v[16];
    float mx = -1e30f;
#pragma unroll
    for (int tl = 0; tl < 16; tl++) { v[tl] = sacc[tl][r] * 0.125f; mx = fmaxf(mx, v[tl]); }
#pragma unroll
    for (int mk = 1; mk < 16; mk <<= 1) mx = fmaxf(mx, __shfl_xor(mx, mk, 64));
    float sum = 0.f;
#pragma unroll
    for (int tl = 0; tl < 16; tl++) { v[tl] = __expf(v[tl] - mx); sum += v[tl]; }
#pragma unroll
    for (int mk = 1; mk < 16; mk <<= 1) sum += __shfl_xor(sum, mk, 64);
    float inv = 1.f / sum;
    const int qrow = w * 16 + kq * 4 + r;
#pragma unroll
    for (int tl = 0; tl < 16; tl++) P[qrow * 264 + tl * 16 + ml] = f2bu(v[tl] * inv);
  }
  __syncthreads();

  {
    const int row_l = w * 16 + (lane >> 2);
    const int cp0 = (lane & 3) * 64;
    u16* dst = Pg + ((size_t)(b * 8 + h) * 256 + q0 + row_l) * 256 + cp0;
    const u16* srcl = &P[row_l * 264 + cp0];
#pragma unroll
    for (int i = 0; i < 8; i++) *(uint4*)(dst + i * 8) = *(const uint4*)(srcl + i * 8);
  }

  f32x4 oacc[4];
#pragma unroll
  for (int j = 0; j < 4; j++) oacc[j] = (f32x4){0.f, 0.f, 0.f, 0.f};
  for (int half = 0; half < 2; half++) {
    __syncthreads();
    {
      const u16* src = VT + ((size_t)(b * 8 + h) * 64 + srow) * 256 + half * 128 + spart * 32;
#pragma unroll
      for (int i = 0; i < 4; i++)
        *(uint4*)&kv[srow * 136 + spart * 32 + i * 8] = *(const uint4*)(src + i * 8);
    }
    __syncthreads();
#pragma unroll
    for (int st = 0; st < 4; st++) {
      short8 ap = *(const short8*)&P[(w * 16 + ml) * 264 + half * 128 + st * 32 + kq * 8];
#pragma unroll
      for (int j = 0; j < 4; j++) {
        short8 bv = *(const short8*)&kv[(j * 16 + ml) * 136 + st * 32 + kq * 8];
        oacc[j] = mfma16(ap, bv, oacc[j]);
      }
    }
  }

#pragma unroll
  for (int j = 0; j < 4; j++) {
    const int d = h * 64 + j * 16 + ml;
#pragma unroll
    for (int r = 0; r < 4; r++) {
      const int tok = b * 256 + q0 + w * 16 + kq * 4 + r;
      CTX16[(size_t)tok * 512 + d] = f2bu(oacc[j][r]);
    }
  }
}

// ---------------- attn_w = softmax(mean over heads of Pg) ----------------
__global__ __launch_bounds__(256) void k_attnw(const u16* __restrict__ Pg, float* __restrict__ AW)
{
  const int t = threadIdx.x;
  const int qt = blockIdx.x, b = blockIdx.y;
  const int row = t >> 4, seg = t & 15;
  const int q = qt * 16 + row;
  float vals[16];
#pragma unroll
  for (int i = 0; i < 16; i++) vals[i] = 0.f;
#pragma unroll
  for (int h = 0; h < 8; h++) {
    const u16* src = Pg + ((size_t)(b * 8 + h) * 256 + q) * 256 + seg * 16;
    uint4 u0 = *(const uint4*)src;
    uint4 u1 = *(const uint4*)(src + 8);
    float f0[8], f1[8];
    unp8(u0, f0); unp8(u1, f1);
#pragma unroll
    for (int i = 0; i < 8; i++) { vals[i] += f0[i]; vals[8 + i] += f1[i]; }
  }
  float vmax = -1e30f;
#pragma unroll
  for (int i = 0; i < 16; i++) { vals[i] *= 0.125f; vmax = fmaxf(vmax, vals[i]); }
#pragma unroll
  for (int mk = 1; mk < 16; mk <<= 1) vmax = fmaxf(vmax, __shfl_xor(vmax, mk, 64));
  float ssum = 0.f;
#pragma unroll
  for (int i = 0; i < 16; i++) { vals[i] = __expf(vals[i] - vmax); ssum += vals[i]; }
#pragma unroll
  for (int mk = 1; mk < 16; mk <<= 1) ssum += __shfl_xor(ssum, mk, 64);
  float inv = 1.f / ssum;
  float* orow = AW + (size_t)(b * 256 + q) * 256 + seg * 16;
#pragma unroll
  for (int i = 0; i < 16; i++) orow[i] = vals[i] * inv;
}

// ---------------- router: 256 blocks x 32 rows ----------------
DEVFN int rwidx(int k, int e) { return k * 8 + e + (k >> 6) * 4; }

__global__ __launch_bounds__(256) void k_router(const float* __restrict__ XNp, const float* __restrict__ rw,
    const float* __restrict__ rb, float* __restrict__ gates, int* __restrict__ topi,
    int* __restrict__ cnt, float* __restrict__ imps)
{
  __shared__ float rws[4128];
  const int t = threadIdx.x;
  for (int i = t; i < 4096; i += 256) rws[rwidx(i >> 3, i & 7)] = rw[i];
  __syncthreads();
  const int w = t >> 6, l = t & 63;
  const int e = l & 7, ch = l >> 3;
  float impAcc = 0.f; int cntAcc = 0;
  const int row0 = blockIdx.x * 32 + w * 8;   // 8 rows per wave
  for (int r = 0; r < 8; r++) {
    const int row = row0 + r;
    const float* xr = XNp + (size_t)row * 512 + ch * 64;
    float s = 0.f;
#pragma unroll 8
    for (int j = 0; j < 64; j++) s = fmaf(xr[j], rws[rwidx(ch * 64 + j, e)], s);
    s += __shfl_xor(s, 8, 64);
    s += __shfl_xor(s, 16, 64);
    s += __shfl_xor(s, 32, 64);
    s += rb[e];
    float p[8];
#pragma unroll
    for (int i = 0; i < 8; i++) p[i] = __shfl(s, (l & 56) | i, 64);
    float mx = p[0];
#pragma unroll
    for (int i = 1; i < 8; i++) mx = fmaxf(mx, p[i]);
    float sum = 0.f;
#pragma unroll
    for (int i = 0; i < 8; i++) { p[i] = __expf(p[i] - mx); sum += p[i]; }
    float inv = 1.f / sum;
#pragma unroll
    for (int i = 0; i < 8; i++) p[i] *= inv;
    int t0 = 0; float v0 = p[0];
#pragma unroll
    for (int i = 1; i < 8; i++) if (p[i] > v0) { v0 = p[i]; t0 = i; }
    int t1 = -1; float v1 = -1.f;
#pragma unroll
    for (int i = 0; i < 8; i++) if (i != t0 && p[i] > v1) { v1 = p[i]; t1 = i; }
    if (l < 8) { impAcc += p[e]; cntAcc += (t0 == e) + (t1 == e); }
    if (l == 0) {
      gates[(size_t)row * 2] = v0; gates[(size_t)row * 2 + 1] = v1;
      topi[(size_t)row * 2] = t0;  topi[(size_t)row * 2 + 1] = t1;
    }
  }
  if (l < 8) { atomicAdd(&imps[e], impAcc); atomicAdd(&cnt[e], cntAcc); }
}

__global__ void k_scan(const int* __restrict__ cnt, int* __restrict__ basep, int* __restrict__ curs) {
  if (threadIdx.x == 0) {
    int a = 0;
    for (int e = 0; e < 8; e++) { basep[e] = a; a += cnt[e]; }
  }
  if (threadIdx.x < 8) curs[threadIdx.x] = 0;
}

__global__ __launch_bounds__(256) void k_scatter(const int* __restrict__ topi, const int* __restrict__ basep,
    int* __restrict__ cursor, int* __restrict__ rowlist, int* __restrict__ rowpos)
{
  __shared__ int lcnt[8], lbase[8];
  const int t = threadIdx.x;
  if (t < 8) lcnt[t] = 0;
  __syncthreads();
  const int token = blockIdx.x * 256 + t;
  const int e0 = topi[token * 2], e1 = topi[token * 2 + 1];
  const int p0 = atomicAdd(&lcnt[e0], 1);
  const int p1 = atomicAdd(&lcnt[e1], 1);
  __syncthreads();
  if (t < 8) lbase[t] = atomicAdd(&cursor[t], lcnt[t]);
  __syncthreads();
  const int pos0 = basep[e0] + lbase[e0] + p0;
  const int pos1 = basep[e1] + lbase[e1] + p1;
  rowlist[pos0] = token; rowlist[pos1] = token;
  rowpos[token * 2] = pos0; rowpos[token * 2 + 1] = pos1;
}

__global__ void k_loss(const int* __restrict__ cnt, const float* __restrict__ imps,
                       float* __restrict__ lossws, float* __restrict__ out, int phase) {
  if (threadIdx.x == 0 && blockIdx.x == 0) {
    float s = 0.f;
    for (int e = 0; e < 8; e++) s += ((float)cnt[e]) * imps[e];
    s *= 8.f / (8192.f * 8192.f);
    if (phase == 0) *lossws = s;
    else out[0] = *lossws + s;
  }
}

// ---------------- MFMA expert GEMM1 ----------------
__global__ __launch_bounds__(256) void k_mg1(const u16* __restrict__ XNB, const u16* __restrict__ W1T,
    const float* __restrict__ B1, u16* __restrict__ H,
    const int* __restrict__ rowlist, const int* __restrict__ basep, const int* __restrict__ cntp)
{
  int bx, by, bz; xcd_swz(bx, by, bz);
  const int e = bz;
  const int cnt = cntp[e];
  const int m0 = by * 128;
  if (m0 >= cnt) return;
  const int base = basep[e];
  const int n0 = bx * 128;
  __shared__ alignas(16) u16 SB[32768];
  __shared__ int rl[128];
  const int t = threadIdx.x;
  if (t < 128) rl[t] = rowlist[base + min(m0 + t, cnt - 1)];
  __syncthreads();
  const int widx = t >> 6, lane = t & 63;
  const int wm = (widx & 1) * 64, wn = (widx >> 1) * 64;
  const int ml = lane & 15, kq = lane >> 4;
  const u16* wt = W1T + (size_t)e * (2048 * 512);
  const u16* agp[4]; const u16* bgp[4];
#pragma unroll
  for (int q = 0; q < 4; q++) {
    const int slot = q * 256 + t;
    const int row = slot >> 3;
    const int c = (slot & 7) ^ (row & 7);
    agp[q] = XNB + (size_t)rl[row] * 512 + c * 8;
    bgp[q] = wt + (size_t)(n0 + row) * 512 + c * 8;
  }
  f32x4 acc[4][4];
#pragma unroll
  for (int i = 0; i < 4; i++)
#pragma unroll
    for (int j = 0; j < 4; j++) acc[i][j] = (f32x4){0.f, 0.f, 0.f, 0.f};
  mma_loop(acc, agp, bgp, SB, 512, wm, wn, ml, kq, widx);

  __syncthreads();
  float* ep = (float*)SB + widx * (16 * 68);
  const int er = lane >> 2, ec = (lane & 3) * 16;
  const int gn = n0 + wn + ec;
  float bb[16];
#pragma unroll
  for (int u = 0; u < 4; u++) {
    float4 f = *(const float4*)(B1 + e * 2048 + gn + u * 4);
    bb[u*4]=f.x; bb[u*4+1]=f.y; bb[u*4+2]=f.z; bb[u*4+3]=f.w;
  }
#pragma unroll
  for (int i = 0; i < 4; i++) {
    float v[16];
    ep_xpose(ep, acc[i], kq, ml, er, ec, v);
    const int lr = wm + i * 16 + er;
    if (m0 + lr < cnt) {
      union { u16 h[16]; uint4 q2[2]; } pk;
#pragma unroll
      for (int u = 0; u < 16; u++) pk.h[u] = f2bu(gelu_f(v[u] + bb[u]));
      u16* hp = H + (size_t)(base + m0 + lr) * 2048 + gn;
      *(uint4*)hp = pk.q2[0]; *(uint4*)(hp + 8) = pk.q2[1];
    }
  }
}

// ---------------- MFMA expert GEMM2 ----------------
__global__ __launch_bounds__(256) void k_mg2(const u16* __restrict__ H, const u16* __restrict__ W2T,
    const float* __restrict__ B2, float* __restrict__ YB,
    const int* __restrict__ basep, const int* __restrict__ cntp)
{
  int bx, by, bz; xcd_swz(bx, by, bz);
  const int e = bz;
  const int cnt = cntp[e];
  const int m0 = by * 128;
  if (m0 >= cnt) return;
  const int base = basep[e];
  const int n0 = bx * 128;
  __shared__ alignas(16) u16 SB[32768];
  const int t = threadIdx.x;
  const int widx = t >> 6, lane = t & 63;
  const int wm = (widx & 1) * 64, wn = (widx >> 1) * 64;
  const int ml = lane & 15, kq = lane >> 4;
  const u16* wt = W2T + (size_t)e * (512 * 2048);
  const u16* agp[4]; const u16* bgp[4];
#pragma unroll
  for (int q = 0; q < 4; q++) {
    const int slot = q * 256 + t;
    const int row = slot >> 3;
    const int c = (slot & 7) ^ (row & 7);
    const int gr = min(base + m0 + row, 16383);
    agp[q] = H + (size_t)gr * 2048 + c * 8;
    bgp[q] = wt + (size_t)(n0 + row) * 2048 + c * 8;
  }
  f32x4 acc[4][4];
#pragma unroll
  for (int i = 0; i < 4; i++)
#pragma unroll
    for (int j = 0; j < 4; j++) acc[i][j] = (f32x4){0.f, 0.f, 0.f, 0.f};
  mma_loop(acc, agp, bgp, SB, 2048, wm, wn, ml, kq, widx);

  __syncthreads();
  float* ep = (float*)SB + widx * (16 * 68);
  const int er = lane >> 2, ec = (lane & 3) * 16;
  const int gn = n0 + wn + ec;
  float bb[16];
#pragma unroll
  for (int u = 0; u < 4; u++) {
    float4 f = *(const float4*)(B2 + e * 512 + gn + u * 4);
    bb[u*4]=f.x; bb[u*4+1]=f.y; bb[u*4+2]=f.z; bb[u*4+3]=f.w;
  }
#pragma unroll
  for (int i = 0; i < 4; i++) {
    float v[16];
    ep_xpose(ep, acc[i], kq, ml, er, ec, v);
    const int lr = wm + i * 16 + er;
    if (m0 + lr < cnt) {
      float* yp = YB + (size_t)(base + m0 + lr) * 512 + gn;
#pragma unroll
      for (int u = 0; u < 4; u++) {
        float4 o = {v[u*4]+bb[u*4], v[u*4+1]+bb[u*4+1], v[u*4+2]+bb[u*4+2], v[u*4+3]+bb[u*4+3]};
        *(float4*)(yp + u * 4) = o;
      }
    }
  }
}

// ---------------- combine / fv / cls ----------------
__global__ __launch_bounds__(256) void k_combine(const float* __restrict__ YB, const float* __restrict__ gates,
    const int* __restrict__ rowpos, float* __restrict__ OUT)
{
  const int idx = blockIdx.x * 256 + threadIdx.x;
  const int row = idx >> 9, d = idx & 511;
  const float g0 = gates[row * 2], g1 = gates[row * 2 + 1];
  const int r0 = rowpos[row * 2], r1 = rowpos[row * 2 + 1];
  OUT[idx] = g0 * YB[(size_t)r0 * 512 + d] + g1 * YB[(size_t)r1 * 512 + d];
}

__global__ __launch_bounds__(256) void k_fv(const float* __restrict__ O2, float* __restrict__ FVp, float* __restrict__ outv) {
  const int idx = blockIdx.x * 256 + threadIdx.x;  // 16384
  const int b = idx >> 9, d = idx & 511;
  const float* p = O2 + (size_t)b * 131072 + d;
  float s = 0.f;
  for (int i = 0; i < 256; i++) s += p[i * 512];
  s *= (1.f / 256.f);
  FVp[idx] = s;
  outv[idx] = s;
}

__global__ __launch_bounds__(256) void k_cls(const float* __restrict__ FVp, const float* __restrict__ W,
    const float* __restrict__ bias, float* __restrict__ outl) {
  const int idx = blockIdx.x * 256 + threadIdx.x;  // 16384
  const int b = idx >> 9, n = idx & 511;
  const float* f = FVp + (size_t)b * 512;
  float s = 0.f;
  for (int d = 0; d < 512; d++) s = fmaf(f[d], W[(size_t)d * 512 + n], s);
  s += bias[n];
  outl[idx] = s;
}

extern "C" void kernel_launch(void* const* d_in, const int* in_sizes, int n_in,
                              void* d_out, int out_size, void* d_ws, size_t ws_size,
                              hipStream_t stream)
{
  (void)in_sizes; (void)n_in; (void)out_size; (void)ws_size;
  const float* x    = (const float*)d_in[0];
  const float* pe_w = (const float*)d_in[1];
  const float* pe_b = (const float*)d_in[2];
  const float* pos  = (const float*)d_in[3];
  const float* ln1g = (const float*)d_in[4];
  const float* ln1b = (const float*)d_in[5];
  const float* lng[2] = {(const float*)d_in[6], (const float*)d_in[8]};
  const float* lnb[2] = {(const float*)d_in[7], (const float*)d_in[9]};
  const float* wq = (const float*)d_in[10]; const float* bq = (const float*)d_in[11];
  const float* wk = (const float*)d_in[12]; const float* bk = (const float*)d_in[13];
  const float* wv = (const float*)d_in[14]; const float* bv = (const float*)d_in[15];
  const float* wo = (const float*)d_in[16]; const float* bo = (const float*)d_in[17];
  const float* m_rw[2] = {(const float*)d_in[18], (const float*)d_in[24]};
  const float* m_rb[2] = {(const float*)d_in[19], (const float*)d_in[25]};
  const float* m_w1[2] = {(const float*)d_in[20], (const float*)d_in[26]};
  const float* m_b1[2] = {(const float*)d_in[21], (const float*)d_in[27]};
  const float* m_w2[2] = {(const float*)d_in[22], (const float*)d_in[28]};
  const float* m_b2[2] = {(const float*)d_in[23], (const float*)d_in[29]};
  const float* cls_w = (const float*)d_in[30];
  const float* cls_b = (const float*)d_in[31];

  float* ws = (float*)d_ws;
  u16* XP    = (u16*)(ws + OF_PATCH);
  float* ebuf = ws + OF_E;
  float* xn   = ws + OF_XN;
  u16* Q16   = (u16*)(ws + OF_Q16);
  u16* K16   = (u16*)(ws + OF_K16);
  u16* VTb   = (u16*)(ws + OF_VT);
  u16* ctx16 = (u16*)(ws + OF_CTX16);
  u16* peT   = (u16*)(ws + OF_PET);
  u16* wqT   = (u16*)(ws + OF_WQT);
  u16* wkT   = (u16*)(ws + OF_WKT);
  u16* wvT   = (u16*)(ws + OF_WVT);
  u16* woT   = (u16*)(ws + OF_WOT);
  u16* Pgb   = (u16*)(ws + OF_O1);   // 32MB, dead after k_attnw
  float* o1   = ws + OF_O1;
  float* o2   = ws + OF_O2;
  float* fv   = ws + OF_FV;
  float* gates = ws + OF_GATES;
  float* imps  = ws + OF_IMPS;
  int* cnt    = (int*)(ws + OF_CNT);
  int* basep  = (int*)(ws + OF_BASE);
  int* curs   = (int*)(ws + OF_CURS);
  float* lossws = ws + OF_LOSS;
  int* topi   = (int*)(ws + OF_TOPI);
  int* rowpos = (int*)(ws + OF_RPOS);
  int* rowlist= (int*)(ws + OF_RLIST);
  u16* Hbuf  = (u16*)(ws + OF_Q);    // MoE overlay on [OF_Q, OF_O1)
  float* YB  = ws + OF_PATCH;        // MoE overlay
  u16* XNB   = (u16*)(ws + OF_PATCH);// bf16 xn (XP dead post-pe-GEMM)
  u16* W1T   = (u16*)(ws + OF_O1);   // MoE overlay (after Pg dead)
  u16* W2T   = (u16*)(ws + OF_O2);

  float* out = (float*)d_out;
  float* out_logits = out;
  float* out_fv     = out + 16384;
  float* out_loss   = out + 32768;
  float* out_attnw  = out + 32769;

  // ---- dense weight prep ----
  k_wcvtd<<<dim3(20, 16), 256, 0, stream>>>(pe_w, peT, 588, 640);
  k_wcvtd<<<dim3(16, 16), 256, 0, stream>>>(wq, wqT, 512, 512);
  k_wcvtd<<<dim3(16, 16), 256, 0, stream>>>(wk, wkT, 512, 512);
  k_wcvtd<<<dim3(16, 16), 256, 0, stream>>>(wv, wvT, 512, 512);
  k_wcvtd<<<dim3(16, 16), 256, 0, stream>>>(wo, woT, 512, 512);

  k_patchify<<<20480, 256, 0, stream>>>(x, XP);
  k_bgemm<0><<<dim3(4, 64), 256, 0, stream>>>(XP, peT, pe_b, ebuf, nullptr, pos, 640);
  k_ln<<<8192, 256, 0, stream>>>(ebuf, xn, XNB, ln1g, ln1b);
  k_bgemm<1><<<dim3(4, 64), 256, 0, stream>>>(XNB, wqT, bq, nullptr, Q16, nullptr, 512);
  k_bgemm<1><<<dim3(4, 64), 256, 0, stream>>>(XNB, wkT, bk, nullptr, K16, nullptr, 512);
  k_bgemm<3><<<dim3(4, 64), 256, 0, stream>>>(XNB, wvT, bv, nullptr, VTb, nullptr, 512);
  k_fattn<<<dim3(4, 8, 32), 256, 0, stream>>>(Q16, K16, VTb, ctx16, Pgb);
  k_attnw<<<dim3(16, 32), 256, 0, stream>>>(Pgb, out_attnw);
  k_bgemm<2><<<dim3(4, 64), 256, 0, stream>>>(ctx16, woT, bo, ebuf, nullptr, nullptr, 512);

  const float* moe_in[2] = {ebuf, o1};
  float* moe_out[2] = {o1, o2};
  for (int mi = 0; mi < 2; mi++) {
    hipMemsetAsync(imps, 0, 64, stream);   // zero imps(32B) + cnt(32B)
    k_ln<<<8192, 256, 0, stream>>>(moe_in[mi], xn, XNB, lng[mi], lnb[mi]);
    // weight cvt AFTER LN: layer-2 must consume o1 before W1T overlay clobbers it
    k_wcvt<<<dim3(16, 64, 8), 256, 0, stream>>>(m_w1[mi], W1T, 512, 2048);
    k_wcvt<<<dim3(64, 16, 8), 256, 0, stream>>>(m_w2[mi], W2T, 2048, 512);
    k_router<<<256, 256, 0, stream>>>(xn, m_rw[mi], m_rb[mi], gates, topi, cnt, imps);
    k_scan<<<1, 64, 0, stream>>>(cnt, basep, curs);
    k_scatter<<<32, 256, 0, stream>>>(topi, basep, curs, rowlist, rowpos);
    k_loss<<<1, 64, 0, stream>>>(cnt, imps, lossws, out_loss, mi);
    k_mg1<<<dim3(16, 64, 8), 256, 0, stream>>>(XNB, W1T, m_b1[mi], Hbuf, rowlist, basep, cnt);
    k_mg2<<<dim3(4, 64, 8), 256, 0, stream>>>(Hbuf, W2T, m_b2[mi], YB, basep, cnt);
    k_combine<<<16384, 256, 0, stream>>>(YB, gates, rowpos, moe_out[mi]);
  }
  k_fv<<<64, 256, 0, stream>>>(o2, fv, out_fv);
  k_cls<<<64, 256, 0, stream>>>(fv, cls_w, cls_b, out_logits);
}

// Round 7
// 786.317 us; speedup vs baseline: 1.0564x; 1.0564x over previous
//
#include <hip/hip_runtime.h>
#include <hip/hip_bf16.h>

using bf16 = __hip_bfloat16;
typedef unsigned short u16;
typedef __attribute__((ext_vector_type(8))) short short8;
typedef __attribute__((ext_vector_type(4))) float f32x4;

#define DEVFN __device__ __forceinline__

DEVFN u16 f2bu(float v) { return __builtin_bit_cast(u16, __float2bfloat16(v)); }
DEVFN float us2f(u16 u) { union { unsigned int i; float f; } x; x.i = ((unsigned int)u) << 16; return x.f; }
DEVFN void unp8(uint4 u, float* f) {
  f[0]=us2f(u.x & 0xffffu); f[1]=us2f(u.x >> 16);
  f[2]=us2f(u.y & 0xffffu); f[3]=us2f(u.y >> 16);
  f[4]=us2f(u.z & 0xffffu); f[5]=us2f(u.z >> 16);
  f[6]=us2f(u.w & 0xffffu); f[7]=us2f(u.w >> 16);
}

DEVFN f32x4 mfma16(short8 a, short8 b, f32x4 c) {
  return __builtin_amdgcn_mfma_f32_16x16x32_bf16(a, b, c, 0, 0, 0);
}

// async global->LDS, 16B per lane; LDS dest = wave-uniform base + lane*16
DEVFN void gl16(const u16* g, u16* l) {
  __builtin_amdgcn_global_load_lds((const __attribute__((address_space(1))) void*)g,
                                   (__attribute__((address_space(3))) void*)l, 16, 0, 0);
}

// fast exact-GELU: erf via Abramowitz-Stegun 7.1.26 (|eps|<=1.5e-7), branch-free.
DEVFN float gelu_f(float v) {
  float z = v * 0.70710678118654752f;
  float a = __builtin_fabsf(z);
  float t = __builtin_amdgcn_rcpf(__builtin_fmaf(0.3275911f, a, 1.0f));
  float q = __builtin_fmaf(t, 1.061405429f, -1.453152027f);
  q = __builtin_fmaf(t, q, 1.421413741f);
  q = __builtin_fmaf(t, q, -0.284496736f);
  q = __builtin_fmaf(t, q, 0.254829592f);
  float e = __expf(-z * z);
  float y = __builtin_fmaf(-q * t, e, 1.0f);   // erf(|z|)
  float er = __builtin_copysignf(y, z);
  return 0.5f * v * (1.0f + er);
}

// T1 CHUNKED XCD swizzle (HK chiplet_transform_chunked): a chunk = the
// gridDim.x n-sibling blocks of one (m[,e]) tile -> same XCD (A-panel L2
// locality); chunks round-robin across the 8 XCDs -> per-XCD load is
// ~total/8 from EVERY expert. Bijective iff (nwg/8) % gridDim.x == 0
// (mg1: 1024/16, mg2: 256/4, bgemm: 32/4 — all integer).
DEVFN void xcd_swz(int& bx, int& by, int& bz) {
  const int nx = gridDim.x, ny = gridDim.y;
  const int orig = blockIdx.x + nx * (blockIdx.y + ny * blockIdx.z);
  const int x = orig & 7, k = orig >> 3;
  const int kc = k / nx, kp = k - kc * nx;
  const int c = x + 8 * kc;          // chunk id in [0, nwg/nx)
  bx = kp;
  by = c % ny;
  bz = c / ny;
}

// ---------------- workspace layout (float element offsets) ----------------
static constexpr size_t OF_PATCH = 0;          // XP bf16 [8192,640] = 2,621,440 fl ; later XNB bf16 + YB f32
static constexpr size_t OF_E     = 4816896;    // ebuf f32 [8192,512]
static constexpr size_t OF_XN    = 9011200;    // xn f32 [8192,512]
static constexpr size_t OF_Q     = 13205504;
static constexpr size_t OF_FV    = 38371328;   // 32*512
static constexpr size_t OF_GATES = 38387712;   // 8192*2
static constexpr size_t OF_IMPS  = 38404096;   // 8 f32 (memset with CNT: 64B)
static constexpr size_t OF_CNT   = 38404104;   // 8 i32
static constexpr size_t OF_BASE  = 38404112;   // 8 i32
static constexpr size_t OF_CURS  = 38404120;   // 8 i32
static constexpr size_t OF_LOSS  = 38404128;   // 1 f32 (+pad)
static constexpr size_t OF_TOPI  = 38404136;   // 8192*2 i32
static constexpr size_t OF_RPOS  = 38420520;   // 8192*2 i32
static constexpr size_t OF_RLIST = 38436904;   // 16384 i32
// Pre-MoE sublayout of [OF_Q, OF_O1):
static constexpr size_t OF_Q16   = 13205504;   // bf16 [8192,512]
static constexpr size_t OF_K16   = 15302656;
static constexpr size_t OF_VT    = 17399808;   // bf16 [32,8,64,256]
static constexpr size_t OF_CTX16 = 19496960;   // bf16 [8192,512]
static constexpr size_t OF_PET   = 21594112;   // bf16 [512,640]
static constexpr size_t OF_WQT   = 21757952;   // bf16 [512,512] each
static constexpr size_t OF_WKT   = 21889024;
static constexpr size_t OF_WVT   = 22020096;
static constexpr size_t OF_WOT   = 22151168;   // ends 22282240 < OF_O1
static constexpr size_t OF_O1    = 29982720;   // o1 f32 ; earlier Pg bf16 spans O1..FV ; W1T overlay
static constexpr size_t OF_O2    = 34177024;   // o2 f32 ; W2T overlay
// MoE overlays: H (bf16 16384x2048) on [OF_Q, OF_O1); YB f32 on [0, 8388608); XNB bf16 on [0, 2097152)

// ---------------- patchify: x[B,3,224,224] -> XP bf16 [8192,640] (zero-pad 588..639) ----------------
__global__ __launch_bounds__(256) void k_patchify(const float* __restrict__ x, u16* __restrict__ XP) {
  int idx = blockIdx.x * 256 + threadIdx.x;
  if (idx >= 8192 * 640) return;
  int row = idx / 640, j = idx - row * 640;
  u16 v = 0;
  if (j < 588) {
    int b = row >> 8, s = row & 255;
    int hh = s >> 4, ww = s & 15;
    int c = j % 3, tt = j / 3;
    int p2 = tt % 14, p1 = tt / 14;
    int src = ((b * 3 + c) * 224 + hh * 14 + p1) * 224 + (ww * 14 + p2);
    v = f2bu(x[src]);
  }
  XP[idx] = v;
}

// ---------------- dense weight cvt+transpose: W[K,512] f32 -> WT[512,KP] bf16 ----------------
__global__ __launch_bounds__(256) void k_wcvtd(const float* __restrict__ W, u16* __restrict__ WT, int K, int KP)
{
  __shared__ float s[32][33];
  const int t = threadIdx.x;
  const int tx = t & 31, ty = t >> 5;
  const int k0 = blockIdx.x * 32, n0 = blockIdx.y * 32;
#pragma unroll
  for (int i = 0; i < 4; i++) {
    int kk = k0 + ty + i * 8;
    s[ty + i * 8][tx] = (kk < K) ? W[(size_t)kk * 512 + n0 + tx] : 0.f;
  }
  __syncthreads();
#pragma unroll
  for (int i = 0; i < 4; i++) WT[(size_t)(n0 + ty + i * 8) * KP + k0 + tx] = f2bu(s[tx][ty + i * 8]);
}

// ---------------- MoE weight cvt+transpose (per expert): W[K,N] f32 -> Wt[N,K] bf16 ----------------
__global__ __launch_bounds__(256) void k_wcvt(const float* __restrict__ W, u16* __restrict__ Wt, int K, int N)
{
  __shared__ float s[32][33];
  const int t = threadIdx.x;
  const int tx = t & 31, ty = t >> 5;
  const int k0 = blockIdx.x * 32, n0 = blockIdx.y * 32;
  const size_t es = (size_t)K * N;
  const float* We = W + (size_t)blockIdx.z * es;
  u16* Wte = Wt + (size_t)blockIdx.z * es;
#pragma unroll
  for (int i = 0; i < 4; i++) s[ty + i * 8][tx] = We[(size_t)(k0 + ty + i * 8) * N + n0 + tx];
  __syncthreads();
#pragma unroll
  for (int i = 0; i < 4; i++) Wte[(size_t)(n0 + ty + i * 8) * K + k0 + tx] = f2bu(s[tx][ty + i * 8]);
}

// ======== shared MFMA engine pieces ========
// Catalog-minimum 2-phase (T3 recipe): per K-step
//   { stage(t+1 -> other buf); ds_read+MFMA(t); vmcnt(0); barrier }
#define WAIT_VM0  asm volatile("s_waitcnt vmcnt(0)" ::: "memory")
#define BARRIER   __builtin_amdgcn_s_barrier()

// ---- 4-wave (256-thread) engine, used by dense k_bgemm ----
DEVFN void mma_stage(const u16* const agp[4], const u16* const bgp[4],
                     u16* Asb, u16* Bsb, int k0, int widx)
{
#pragma unroll
  for (int q = 0; q < 4; q++) {
    gl16(agp[q] + k0, Asb + (q * 256 + widx * 64) * 8);
    gl16(bgp[q] + k0, Bsb + (q * 256 + widx * 64) * 8);
  }
}

DEVFN void mma_step(f32x4 acc[4][4], const u16* As, const u16* Bs,
                    int wm, int wn, int ml, int kq)
{
  __builtin_amdgcn_s_setprio(1);   // T5: favor compute-phase waves
#pragma unroll
  for (int ks = 0; ks < 2; ks++) {
    const int c = ks * 4 + kq;
    short8 af[4], bf[4];
#pragma unroll
    for (int i = 0; i < 4; i++) {
      const int row = wm + i * 16 + ml;
      af[i] = *(const short8*)&As[row * 64 + ((c ^ (row & 7)) << 3)];
    }
#pragma unroll
    for (int j = 0; j < 4; j++) {
      const int row = wn + j * 16 + ml;
      bf[j] = *(const short8*)&Bs[row * 64 + ((c ^ (row & 7)) << 3)];
    }
#pragma unroll
    for (int i = 0; i < 4; i++)
#pragma unroll
      for (int j = 0; j < 4; j++) acc[i][j] = mfma16(af[i], bf[j], acc[i][j]);
  }
  __builtin_amdgcn_s_setprio(0);
}

DEVFN void mma_loop(f32x4 acc[4][4], const u16* const agp[4], const u16* const bgp[4],
                    u16* SB, int K, int wm, int wn, int ml, int kq, int widx)
{
  const int NT = K >> 6;
  mma_stage(agp, bgp, SB, SB + 8192, 0, widx); // tile 0 -> buf0
  WAIT_VM0;
  BARRIER;                                     // tile 0 resident for all waves
  int cur = 0;
  for (int t = 0; t + 1 < NT; ++t) {
    u16* Nx = SB + ((cur ^ 1) << 14);
    mma_stage(agp, bgp, Nx, Nx + 8192, (t + 1) << 6, widx);  // stage t+1
    u16* Cu = SB + (cur << 14);
    mma_step(acc, Cu, Cu + 8192, wm, wn, ml, kq);            // compute t
    WAIT_VM0;                                                 // t+1 landed
    BARRIER;                                                  // all reads(t) done
    cur ^= 1;
  }
  u16* Cu = SB + (cur << 14);
  mma_step(acc, Cu, Cu + 8192, wm, wn, ml, kq);               // last tile
}

// ---- 8-wave (512-thread) engine, used by k_mg1/k_mg2 ----
// Same 128x128 tile, same 2-phase sync; 8 waves as 2(M)x4(N), per-wave
// sub-tile 64x32, acc[4][2]. 2 blocks/CU * 8 waves = 16 waves/CU (4/SIMD):
// when one block drains at its barrier, the co-resident block feeds the
// MFMA pipe (m114 wave-level overlap, doubled).
DEVFN void mma_stage8(const u16* const agp[2], const u16* const bgp[2],
                      u16* Asb, u16* Bsb, int k0, int widx)
{
#pragma unroll
  for (int q = 0; q < 2; q++) {
    gl16(agp[q] + k0, Asb + (q * 512 + widx * 64) * 8);
    gl16(bgp[q] + k0, Bsb + (q * 512 + widx * 64) * 8);
  }
}

DEVFN void mma_step8(f32x4 acc[4][2], const u16* As, const u16* Bs,
                     int wm, int wn, int ml, int kq)
{
  __builtin_amdgcn_s_setprio(1);
#pragma unroll
  for (int ks = 0; ks < 2; ks++) {
    const int c = ks * 4 + kq;
    short8 af[4], bf[2];
#pragma unroll
    for (int i = 0; i < 4; i++) {
      const int row = wm + i * 16 + ml;
      af[i] = *(const short8*)&As[row * 64 + ((c ^ (row & 7)) << 3)];
    }
#pragma unroll
    for (int j = 0; j < 2; j++) {
      const int row = wn + j * 16 + ml;
      bf[j] = *(const short8*)&Bs[row * 64 + ((c ^ (row & 7)) << 3)];
    }
#pragma unroll
    for (int i = 0; i < 4; i++)
#pragma unroll
      for (int j = 0; j < 2; j++) acc[i][j] = mfma16(af[i], bf[j], acc[i][j]);
  }
  __builtin_amdgcn_s_setprio(0);
}

DEVFN void mma_loop8(f32x4 acc[4][2], const u16* const agp[2], const u16* const bgp[2],
                     u16* SB, int K, int wm, int wn, int ml, int kq, int widx)
{
  const int NT = K >> 6;
  mma_stage8(agp, bgp, SB, SB + 8192, 0, widx);
  WAIT_VM0;
  BARRIER;
  int cur = 0;
  for (int t = 0; t + 1 < NT; ++t) {
    u16* Nx = SB + ((cur ^ 1) << 14);
    mma_stage8(agp, bgp, Nx, Nx + 8192, (t + 1) << 6, widx);
    u16* Cu = SB + (cur << 14);
    mma_step8(acc, Cu, Cu + 8192, wm, wn, ml, kq);
    WAIT_VM0;
    BARRIER;
    cur ^= 1;
  }
  u16* Cu = SB + (cur << 14);
  mma_step8(acc, Cu, Cu + 8192, wm, wn, ml, kq);
}

// Wave-private accumulator transpose through LDS (4-wave: 16x64 block, stride 68).
DEVFN void ep_xpose(float* ep, const f32x4* ai, int kq, int ml, int er, int ec, float* v)
{
#pragma unroll
  for (int j = 0; j < 4; j++)
#pragma unroll
    for (int r = 0; r < 4; r++)
      ep[(kq * 4 + r) * 68 + j * 16 + ml] = ai[j][r];
#pragma unroll
  for (int u = 0; u < 4; u++) {
    float4 f = *(const float4*)&ep[er * 68 + ec + u * 4];
    v[u * 4 + 0] = f.x; v[u * 4 + 1] = f.y; v[u * 4 + 2] = f.z; v[u * 4 + 3] = f.w;
  }
}

// 8-wave variant: 16x32 block per i, stride 36 floats (144B, 16B-multiple).
// ec = (lane&3)*8; reads two float4 -> v[8]. Wave-private, no barrier.
DEVFN void ep_xpose8(float* ep, const f32x4* ai, int kq, int ml, int er, int ec, float* v)
{
#pragma unroll
  for (int j = 0; j < 2; j++)
#pragma unroll
    for (int r = 0; r < 4; r++)
      ep[(kq * 4 + r) * 36 + j * 16 + ml] = ai[j][r];
#pragma unroll
  for (int u = 0; u < 2; u++) {
    float4 f = *(const float4*)&ep[er * 36 + ec + u * 4];
    v[u * 4 + 0] = f.x; v[u * 4 + 1] = f.y; v[u * 4 + 2] = f.z; v[u * 4 + 3] = f.w;
  }
}

// ---------------- dense MFMA GEMM (4-wave, unchanged) ----------------
template<int MODE>
__global__ __launch_bounds__(256) void k_bgemm(const u16* __restrict__ A, const u16* __restrict__ BT,
    const float* __restrict__ bias, float* __restrict__ Cf, u16* __restrict__ O16,
    const float* __restrict__ pos, int K)
{
  int bx, by, bz; xcd_swz(bx, by, bz);
  const int m0 = by * 128, n0 = bx * 128;
  __shared__ alignas(16) u16 SB[32768];
  const int t = threadIdx.x;
  const int widx = t >> 6, lane = t & 63;
  const int wm = (widx & 1) * 64, wn = (widx >> 1) * 64;
  const int ml = lane & 15, kq = lane >> 4;
  const u16* agp[4]; const u16* bgp[4];
#pragma unroll
  for (int q = 0; q < 4; q++) {
    const int slot = q * 256 + t;
    const int row = slot >> 3;
    const int c = (slot & 7) ^ (row & 7);
    agp[q] = A + (size_t)(m0 + row) * K + c * 8;
    bgp[q] = BT + (size_t)(n0 + row) * K + c * 8;
  }
  f32x4 acc[4][4];
#pragma unroll
  for (int i = 0; i < 4; i++)
#pragma unroll
    for (int j = 0; j < 4; j++) acc[i][j] = (f32x4){0.f, 0.f, 0.f, 0.f};
  mma_loop(acc, agp, bgp, SB, K, wm, wn, ml, kq, widx);

  if (MODE == 3) {
#pragma unroll
    for (int j = 0; j < 4; j++) {
      const int n = n0 + wn + j * 16 + ml;
      const float bv = bias[n];
      const int h = n >> 6, d = n & 63;
#pragma unroll
      for (int i = 0; i < 4; i++) {
        const int mb = m0 + wm + i * 16 + kq * 4;
        const int b = mb >> 8, s0 = mb & 255;
        ushort4 w4;
        w4.x = f2bu(acc[i][j][0] + bv); w4.y = f2bu(acc[i][j][1] + bv);
        w4.z = f2bu(acc[i][j][2] + bv); w4.w = f2bu(acc[i][j][3] + bv);
        *(ushort4*)(O16 + ((size_t)(b * 8 + h) * 64 + d) * 256 + s0) = w4;
      }
    }
    return;
  }

  __syncthreads();   // all waves past final buf reads; ep region reusable
  float* ep = (float*)SB + widx * (16 * 68);
  const int er = lane >> 2, ec = (lane & 3) * 16;
  const int gn = n0 + wn + ec;
  float bb[16];
#pragma unroll
  for (int u = 0; u < 4; u++) {
    float4 f = *(const float4*)(bias + gn + u * 4);
    bb[u*4]=f.x; bb[u*4+1]=f.y; bb[u*4+2]=f.z; bb[u*4+3]=f.w;
  }
#pragma unroll
  for (int i = 0; i < 4; i++) {
    float v[16];
    ep_xpose(ep, acc[i], kq, ml, er, ec, v);
    const int gm = m0 + wm + i * 16 + er;
    if (MODE == 0) {
      const float* pr = pos + (size_t)(gm & 255) * 512 + gn;
      float* cp = Cf + (size_t)gm * 512 + gn;
#pragma unroll
      for (int u = 0; u < 4; u++) {
        float4 p = *(const float4*)(pr + u * 4);
        float4 o = {v[u*4]+bb[u*4]+p.x, v[u*4+1]+bb[u*4+1]+p.y, v[u*4+2]+bb[u*4+2]+p.z, v[u*4+3]+bb[u*4+3]+p.w};
        *(float4*)(cp + u * 4) = o;
      }
    } else if (MODE == 1) {
      union { u16 h[16]; uint4 q2[2]; } pk;
#pragma unroll
      for (int u = 0; u < 16; u++) pk.h[u] = f2bu(v[u] + bb[u]);
      u16* hp = O16 + (size_t)gm * 512 + gn;
      *(uint4*)hp = pk.q2[0]; *(uint4*)(hp + 8) = pk.q2[1];
    } else {  // MODE 2
      float* cp = Cf + (size_t)gm * 512 + gn;
#pragma unroll
      for (int u = 0; u < 4; u++) {
        float4 oldv = *(const float4*)(cp + u * 4);
        float4 o = {oldv.x+v[u*4]+bb[u*4], oldv.y+v[u*4+1]+bb[u*4+1], oldv.z+v[u*4+2]+bb[u*4+2], oldv.w+v[u*4+3]+bb[u*4+3]};
        *(float4*)(cp + u * 4) = o;
      }
    }
  }
}

// ---------------- LayerNorm over D=512 (writes f32 + bf16 copies) ----------------
__global__ __launch_bounds__(256) void k_ln(const float* __restrict__ X, float* __restrict__ Y,
    u16* __restrict__ YB16, const float* __restrict__ g, const float* __restrict__ b)
{
  __shared__ float red[256];
  const int row = blockIdx.x;
  const int t = threadIdx.x;
  const float* xr = X + (size_t)row * 512;
  float x0 = xr[t], x1 = xr[t + 256];
  red[t] = x0 + x1;
  __syncthreads();
  for (int s = 128; s > 0; s >>= 1) { if (t < s) red[t] += red[t + s]; __syncthreads(); }
  float mean = red[0] * (1.f / 512.f);
  __syncthreads();
  float d0 = x0 - mean, d1 = x1 - mean;
  red[t] = d0 * d0 + d1 * d1;
  __syncthreads();
  for (int s = 128; s > 0; s >>= 1) { if (t < s) red[t] += red[t + s]; __syncthreads(); }
  float rs = 1.f / sqrtf(red[0] * (1.f / 512.f) + 1e-5f);
  float y0 = d0 * rs * g[t]       + b[t];
  float y1 = d1 * rs * g[t + 256] + b[t + 256];
  float* yr = Y + (size_t)row * 512;
  yr[t] = y0; yr[t + 256] = y1;
  u16* br16 = YB16 + (size_t)row * 512;
  br16[t] = f2bu(y0); br16[t + 256] = f2bu(y1);
}

// ---------------- MFMA attention (unchanged) ----------------
__global__ __launch_bounds__(256) void k_fattn(const u16* __restrict__ Q16, const u16* __restrict__ K16,
    const u16* __restrict__ VT, u16* __restrict__ CTX16, u16* __restrict__ Pg)
{
  __shared__ u16 P[64 * 264];
  __shared__ u16 kv[64 * 136];
  const int t = threadIdx.x;
  const int qt = blockIdx.x, h = blockIdx.y, b = blockIdx.z;
  const int q0 = qt * 64;
  const int lane = t & 63, w = t >> 6;
  const int ml = lane & 15, kq = lane >> 4;
  const int srow = t >> 2, spart = t & 3;

  const size_t tokq = (size_t)(b * 256 + q0 + w * 16 + ml);
  short8 aq0 = *(const short8*)(Q16 + tokq * 512 + h * 64 + kq * 8);
  short8 aq1 = *(const short8*)(Q16 + tokq * 512 + h * 64 + 32 + kq * 8);

  f32x4 sacc[16];
#pragma unroll
  for (int i = 0; i < 16; i++) sacc[i] = (f32x4){0.f, 0.f, 0.f, 0.f};

  for (int kc = 0; kc < 4; kc++) {
    __syncthreads();
    {
      const u16* src = K16 + (size_t)(b * 256 + kc * 64 + srow) * 512 + h * 64 + spart * 16;
      uint4 v0 = *(const uint4*)src;
      uint4 v1 = *(const uint4*)(src + 8);
      *(uint4*)&kv[srow * 72 + spart * 16] = v0;
      *(uint4*)&kv[srow * 72 + spart * 16 + 8] = v1;
    }
    __syncthreads();
#pragma unroll
    for (int kt = 0; kt < 4; kt++) {
      short8 bk0 = *(const short8*)&kv[(kt * 16 + ml) * 72 + kq * 8];
      short8 bk1 = *(const short8*)&kv[(kt * 16 + ml) * 72 + 32 + kq * 8];
      sacc[kc * 4 + kt] = mfma16(aq0, bk0, sacc[kc * 4 + kt]);
      sacc[kc * 4 + kt] = mfma16(aq1, bk1, sacc[kc * 4 + kt]);
    }
  }

#pragma unroll
  for (int r = 0; r < 4; r++) {
    float v[16];
    float mx = -1e30f;
#pragma unroll
    for (int tl = 0; tl < 16; tl++) { v[tl] = sacc[tl][r] * 0.125f; mx = fmaxf(mx, v[tl]); }
#pragma unroll
    for (int mk = 1; mk < 16; mk <<= 1) mx = fmaxf(mx, __shfl_xor(mx, mk, 64));
    float sum = 0.f;
#pragma unroll
    for (int tl = 0; tl < 16; tl++) { v[tl] = __expf(v[tl] - mx); sum += v[tl]; }
#pragma unroll
    for (int mk = 1; mk < 16; mk <<= 1) sum += __shfl_xor(sum, mk, 64);
    float inv = 1.f / sum;
    const int qrow = w * 16 + kq * 4 + r;
#pragma unroll
    for (int tl = 0; tl < 16; tl++) P[qrow * 264 + tl * 16 + ml] = f2bu(v[tl] * inv);
  }
  __syncthreads();

  {
    const int row_l = w * 16 + (lane >> 2);
    const int cp0 = (lane & 3) * 64;
    u16* dst = Pg + ((size_t)(b * 8 + h) * 256 + q0 + row_l) * 256 + cp0;
    const u16* srcl = &P[row_l * 264 + cp0];
#pragma unroll
    for (int i = 0; i < 8; i++) *(uint4*)(dst + i * 8) = *(const uint4*)(srcl + i * 8);
  }

  f32x4 oacc[4];
#pragma unroll
  for (int j = 0; j < 4; j++) oacc[j] = (f32x4){0.f, 0.f, 0.f, 0.f};
  for (int half = 0; half < 2; half++) {
    __syncthreads();
    {
      const u16* src = VT + ((size_t)(b * 8 + h) * 64 + srow) * 256 + half * 128 + spart * 32;
#pragma unroll
      for (int i = 0; i < 4; i++)
        *(uint4*)&kv[srow * 136 + spart * 32 + i * 8] = *(const uint4*)(src + i * 8);
    }
    __syncthreads();
#pragma unroll
    for (int st = 0; st < 4; st++) {
      short8 ap = *(const short8*)&P[(w * 16 + ml) * 264 + half * 128 + st * 32 + kq * 8];
#pragma unroll
      for (int j = 0; j < 4; j++) {
        short8 bv = *(const short8*)&kv[(j * 16 + ml) * 136 + st * 32 + kq * 8];
        oacc[j] = mfma16(ap, bv, oacc[j]);
      }
    }
  }

#pragma unroll
  for (int j = 0; j < 4; j++) {
    const int d = h * 64 + j * 16 + ml;
#pragma unroll
    for (int r = 0; r < 4; r++) {
      const int tok = b * 256 + q0 + w * 16 + kq * 4 + r;
      CTX16[(size_t)tok * 512 + d] = f2bu(oacc[j][r]);
    }
  }
}

// ---------------- attn_w = softmax(mean over heads of Pg) ----------------
__global__ __launch_bounds__(256) void k_attnw(const u16* __restrict__ Pg, float* __restrict__ AW)
{
  const int t = threadIdx.x;
  const int qt = blockIdx.x, b = blockIdx.y;
  const int row = t >> 4, seg = t & 15;
  const int q = qt * 16 + row;
  float vals[16];
#pragma unroll
  for (int i = 0; i < 16; i++) vals[i] = 0.f;
#pragma unroll
  for (int h = 0; h < 8; h++) {
    const u16* src = Pg + ((size_t)(b * 8 + h) * 256 + q) * 256 + seg * 16;
    uint4 u0 = *(const uint4*)src;
    uint4 u1 = *(const uint4*)(src + 8);
    float f0[8], f1[8];
    unp8(u0, f0); unp8(u1, f1);
#pragma unroll
    for (int i = 0; i < 8; i++) { vals[i] += f0[i]; vals[8 + i] += f1[i]; }
  }
  float vmax = -1e30f;
#pragma unroll
  for (int i = 0; i < 16; i++) { vals[i] *= 0.125f; vmax = fmaxf(vmax, vals[i]); }
#pragma unroll
  for (int mk = 1; mk < 16; mk <<= 1) vmax = fmaxf(vmax, __shfl_xor(vmax, mk, 64));
  float ssum = 0.f;
#pragma unroll
  for (int i = 0; i < 16; i++) { vals[i] = __expf(vals[i] - vmax); ssum += vals[i]; }
#pragma unroll
  for (int mk = 1; mk < 16; mk <<= 1) ssum += __shfl_xor(ssum, mk, 64);
  float inv = 1.f / ssum;
  float* orow = AW + (size_t)(b * 256 + q) * 256 + seg * 16;
#pragma unroll
  for (int i = 0; i < 16; i++) orow[i] = vals[i] * inv;
}

// ---------------- router: 256 blocks x 32 rows ----------------
DEVFN int rwidx(int k, int e) { return k * 8 + e + (k >> 6) * 4; }

__global__ __launch_bounds__(256) void k_router(const float* __restrict__ XNp, const float* __restrict__ rw,
    const float* __restrict__ rb, float* __restrict__ gates, int* __restrict__ topi,
    int* __restrict__ cnt, float* __restrict__ imps)
{
  __shared__ float rws[4128];
  const int t = threadIdx.x;
  for (int i = t; i < 4096; i += 256) rws[rwidx(i >> 3, i & 7)] = rw[i];
  __syncthreads();
  const int w = t >> 6, l = t & 63;
  const int e = l & 7, ch = l >> 3;
  float impAcc = 0.f; int cntAcc = 0;
  const int row0 = blockIdx.x * 32 + w * 8;   // 8 rows per wave
  for (int r = 0; r < 8; r++) {
    const int row = row0 + r;
    const float* xr = XNp + (size_t)row * 512 + ch * 64;
    float s = 0.f;
#pragma unroll 8
    for (int j = 0; j < 64; j++) s = fmaf(xr[j], rws[rwidx(ch * 64 + j, e)], s);
    s += __shfl_xor(s, 8, 64);
    s += __shfl_xor(s, 16, 64);
    s += __shfl_xor(s, 32, 64);
    s += rb[e];
    float p[8];
#pragma unroll
    for (int i = 0; i < 8; i++) p[i] = __shfl(s, (l & 56) | i, 64);
    float mx = p[0];
#pragma unroll
    for (int i = 1; i < 8; i++) mx = fmaxf(mx, p[i]);
    float sum = 0.f;
#pragma unroll
    for (int i = 0; i < 8; i++) { p[i] = __expf(p[i] - mx); sum += p[i]; }
    float inv = 1.f / sum;
#pragma unroll
    for (int i = 0; i < 8; i++) p[i] *= inv;
    int t0 = 0; float v0 = p[0];
#pragma unroll
    for (int i = 1; i < 8; i++) if (p[i] > v0) { v0 = p[i]; t0 = i; }
    int t1 = -1; float v1 = -1.f;
#pragma unroll
    for (int i = 0; i < 8; i++) if (i != t0 && p[i] > v1) { v1 = p[i]; t1 = i; }
    if (l < 8) { impAcc += p[e]; cntAcc += (t0 == e) + (t1 == e); }
    if (l == 0) {
      gates[(size_t)row * 2] = v0; gates[(size_t)row * 2 + 1] = v1;
      topi[(size_t)row * 2] = t0;  topi[(size_t)row * 2 + 1] = t1;
    }
  }
  if (l < 8) { atomicAdd(&imps[e], impAcc); atomicAdd(&cnt[e], cntAcc); }
}

__global__ void k_scan(const int* __restrict__ cnt, int* __restrict__ basep, int* __restrict__ curs) {
  if (threadIdx.x == 0) {
    int a = 0;
    for (int e = 0; e < 8; e++) { basep[e] = a; a += cnt[e]; }
  }
  if (threadIdx.x < 8) curs[threadIdx.x] = 0;
}

__global__ __launch_bounds__(256) void k_scatter(const int* __restrict__ topi, const int* __restrict__ basep,
    int* __restrict__ cursor, int* __restrict__ rowlist, int* __restrict__ rowpos)
{
  __shared__ int lcnt[8], lbase[8];
  const int t = threadIdx.x;
  if (t < 8) lcnt[t] = 0;
  __syncthreads();
  const int token = blockIdx.x * 256 + t;
  const int e0 = topi[token * 2], e1 = topi[token * 2 + 1];
  const int p0 = atomicAdd(&lcnt[e0], 1);
  const int p1 = atomicAdd(&lcnt[e1], 1);
  __syncthreads();
  if (t < 8) lbase[t] = atomicAdd(&cursor[t], lcnt[t]);
  __syncthreads();
  const int pos0 = basep[e0] + lbase[e0] + p0;
  const int pos1 = basep[e1] + lbase[e1] + p1;
  rowlist[pos0] = token; rowlist[pos1] = token;
  rowpos[token * 2] = pos0; rowpos[token * 2 + 1] = pos1;
}

__global__ void k_loss(const int* __restrict__ cnt, const float* __restrict__ imps,
                       float* __restrict__ lossws, float* __restrict__ out, int phase) {
  if (threadIdx.x == 0 && blockIdx.x == 0) {
    float s = 0.f;
    for (int e = 0; e < 8; e++) s += ((float)cnt[e]) * imps[e];
    s *= 8.f / (8192.f * 8192.f);
    if (phase == 0) *lossws = s;
    else out[0] = *lossws + s;
  }
}

// ---------------- MFMA expert GEMM1 (8-wave) ----------------
__global__ __launch_bounds__(512) void k_mg1(const u16* __restrict__ XNB, const u16* __restrict__ W1T,
    const float* __restrict__ B1, u16* __restrict__ H,
    const int* __restrict__ rowlist, const int* __restrict__ basep, const int* __restrict__ cntp)
{
  int bx, by, bz; xcd_swz(bx, by, bz);
  const int e = bz;
  const int cnt = cntp[e];
  const int m0 = by * 128;
  if (m0 >= cnt) return;
  const int base = basep[e];
  const int n0 = bx * 128;
  __shared__ alignas(16) u16 SB[32768];
  __shared__ int rl[128];
  const int t = threadIdx.x;
  if (t < 128) rl[t] = rowlist[base + min(m0 + t, cnt - 1)];
  __syncthreads();
  const int widx = t >> 6, lane = t & 63;
  const int wm = (widx & 1) * 64, wn = (widx >> 1) * 32;
  const int ml = lane & 15, kq = lane >> 4;
  const u16* wt = W1T + (size_t)e * (2048 * 512);
  const u16* agp[2]; const u16* bgp[2];
#pragma unroll
  for (int q = 0; q < 2; q++) {
    const int slot = q * 512 + t;
    const int row = slot >> 3;
    const int c = (slot & 7) ^ (row & 7);
    agp[q] = XNB + (size_t)rl[row] * 512 + c * 8;
    bgp[q] = wt + (size_t)(n0 + row) * 512 + c * 8;
  }
  f32x4 acc[4][2];
#pragma unroll
  for (int i = 0; i < 4; i++)
#pragma unroll
    for (int j = 0; j < 2; j++) acc[i][j] = (f32x4){0.f, 0.f, 0.f, 0.f};
  mma_loop8(acc, agp, bgp, SB, 512, wm, wn, ml, kq, widx);

  __syncthreads();
  float* ep = (float*)SB + widx * (16 * 36);
  const int er = lane >> 2, ec = (lane & 3) * 8;
  const int gn = n0 + wn + ec;
  float bb[8];
#pragma unroll
  for (int u = 0; u < 2; u++) {
    float4 f = *(const float4*)(B1 + e * 2048 + gn + u * 4);
    bb[u*4]=f.x; bb[u*4+1]=f.y; bb[u*4+2]=f.z; bb[u*4+3]=f.w;
  }
#pragma unroll
  for (int i = 0; i < 4; i++) {
    float v[8];
    ep_xpose8(ep, acc[i], kq, ml, er, ec, v);
    const int lr = wm + i * 16 + er;
    if (m0 + lr < cnt) {
      union { u16 h[8]; uint4 q2; } pk;
#pragma unroll
      for (int u = 0; u < 8; u++) pk.h[u] = f2bu(gelu_f(v[u] + bb[u]));
      *(uint4*)(H + (size_t)(base + m0 + lr) * 2048 + gn) = pk.q2;
    }
  }
}

// ---------------- MFMA expert GEMM2 (8-wave) ----------------
__global__ __launch_bounds__(512) void k_mg2(const u16* __restrict__ H, const u16* __restrict__ W2T,
    const float* __restrict__ B2, float* __restrict__ YB,
    const int* __restrict__ basep, const int* __restrict__ cntp)
{
  int bx, by, bz; xcd_swz(bx, by, bz);
  const int e = bz;
  const int cnt = cntp[e];
  const int m0 = by * 128;
  if (m0 >= cnt) return;
  const int base = basep[e];
  const int n0 = bx * 128;
  __shared__ alignas(16) u16 SB[32768];
  const int t = threadIdx.x;
  const int widx = t >> 6, lane = t & 63;
  const int wm = (widx & 1) * 64, wn = (widx >> 1) * 32;
  const int ml = lane & 15, kq = lane >> 4;
  const u16* wt = W2T + (size_t)e * (512 * 2048);
  const u16* agp[2]; const u16* bgp[2];
#pragma unroll
  for (int q = 0; q < 2; q++) {
    const int slot = q * 512 + t;
    const int row = slot >> 3;
    const int c = (slot & 7) ^ (row & 7);
    const int gr = min(base + m0 + row, 16383);
    agp[q] = H + (size_t)gr * 2048 + c * 8;
    bgp[q] = wt + (size_t)(n0 + row) * 2048 + c * 8;
  }
  f32x4 acc[4][2];
#pragma unroll
  for (int i = 0; i < 4; i++)
#pragma unroll
    for (int j = 0; j < 2; j++) acc[i][j] = (f32x4){0.f, 0.f, 0.f, 0.f};
  mma_loop8(acc, agp, bgp, SB, 2048, wm, wn, ml, kq, widx);

  __syncthreads();
  float* ep = (float*)SB + widx * (16 * 36);
  const int er = lane >> 2, ec = (lane & 3) * 8;
  const int gn = n0 + wn + ec;
  float bb[8];
#pragma unroll
  for (int u = 0; u < 2; u++) {
    float4 f = *(const float4*)(B2 + e * 512 + gn + u * 4);
    bb[u*4]=f.x; bb[u*4+1]=f.y; bb[u*4+2]=f.z; bb[u*4+3]=f.w;
  }
#pragma unroll
  for (int i = 0; i < 4; i++) {
    float v[8];
    ep_xpose8(ep, acc[i], kq, ml, er, ec, v);
    const int lr = wm + i * 16 + er;
    if (m0 + lr < cnt) {
      float* yp = YB + (size_t)(base + m0 + lr) * 512 + gn;
#pragma unroll
      for (int u = 0; u < 2; u++) {
        float4 o = {v[u*4]+bb[u*4], v[u*4+1]+bb[u*4+1], v[u*4+2]+bb[u*4+2], v[u*4+3]+bb[u*4+3]};
        *(float4*)(yp + u * 4) = o;
      }
    }
  }
}

// ---------------- combine / fv / cls ----------------
__global__ __launch_bounds__(256) void k_combine(const float* __restrict__ YB, const float* __restrict__ gates,
    const int* __restrict__ rowpos, float* __restrict__ OUT)
{
  const int idx = blockIdx.x * 256 + threadIdx.x;
  const int row = idx >> 9, d = idx & 511;
  const float g0 = gates[row * 2], g1 = gates[row * 2 + 1];
  const int r0 = rowpos[row * 2], r1 = rowpos[row * 2 + 1];
  OUT[idx] = g0 * YB[(size_t)r0 * 512 + d] + g1 * YB[(size_t)r1 * 512 + d];
}

__global__ __launch_bounds__(256) void k_fv(const float* __restrict__ O2, float* __restrict__ FVp, float* __restrict__ outv) {
  const int idx = blockIdx.x * 256 + threadIdx.x;  // 16384
  const int b = idx >> 9, d = idx & 511;
  const float* p = O2 + (size_t)b * 131072 + d;
  float s = 0.f;
  for (int i = 0; i < 256; i++) s += p[i * 512];
  s *= (1.f / 256.f);
  FVp[idx] = s;
  outv[idx] = s;
}

__global__ __launch_bounds__(256) void k_cls(const float* __restrict__ FVp, const float* __restrict__ W,
    const float* __restrict__ bias, float* __restrict__ outl) {
  const int idx = blockIdx.x * 256 + threadIdx.x;  // 16384
  const int b = idx >> 9, n = idx & 511;
  const float* f = FVp + (size_t)b * 512;
  float s = 0.f;
  for (int d = 0; d < 512; d++) s = fmaf(f[d], W[(size_t)d * 512 + n], s);
  s += bias[n];
  outl[idx] = s;
}

extern "C" void kernel_launch(void* const* d_in, const int* in_sizes, int n_in,
                              void* d_out, int out_size, void* d_ws, size_t ws_size,
                              hipStream_t stream)
{
  (void)in_sizes; (void)n_in; (void)out_size; (void)ws_size;
  const float* x    = (const float*)d_in[0];
  const float* pe_w = (const float*)d_in[1];
  const float* pe_b = (const float*)d_in[2];
  const float* pos  = (const float*)d_in[3];
  const float* ln1g = (const float*)d_in[4];
  const float* ln1b = (const float*)d_in[5];
  const float* lng[2] = {(const float*)d_in[6], (const float*)d_in[8]};
  const float* lnb[2] = {(const float*)d_in[7], (const float*)d_in[9]};
  const float* wq = (const float*)d_in[10]; const float* bq = (const float*)d_in[11];
  const float* wk = (const float*)d_in[12]; const float* bk = (const float*)d_in[13];
  const float* wv = (const float*)d_in[14]; const float* bv = (const float*)d_in[15];
  const float* wo = (const float*)d_in[16]; const float* bo = (const float*)d_in[17];
  const float* m_rw[2] = {(const float*)d_in[18], (const float*)d_in[24]};
  const float* m_rb[2] = {(const float*)d_in[19], (const float*)d_in[25]};
  const float* m_w1[2] = {(const float*)d_in[20], (const float*)d_in[26]};
  const float* m_b1[2] = {(const float*)d_in[21], (const float*)d_in[27]};
  const float* m_w2[2] = {(const float*)d_in[22], (const float*)d_in[28]};
  const float* m_b2[2] = {(const float*)d_in[23], (const float*)d_in[29]};
  const float* cls_w = (const float*)d_in[30];
  const float* cls_b = (const float*)d_in[31];

  float* ws = (float*)d_ws;
  u16* XP    = (u16*)(ws + OF_PATCH);
  float* ebuf = ws + OF_E;
  float* xn   = ws + OF_XN;
  u16* Q16   = (u16*)(ws + OF_Q16);
  u16* K16   = (u16*)(ws + OF_K16);
  u16* VTb   = (u16*)(ws + OF_VT);
  u16* ctx16 = (u16*)(ws + OF_CTX16);
  u16* peT   = (u16*)(ws + OF_PET);
  u16* wqT   = (u16*)(ws + OF_WQT);
  u16* wkT   = (u16*)(ws + OF_WKT);
  u16* wvT   = (u16*)(ws + OF_WVT);
  u16* woT   = (u16*)(ws + OF_WOT);
  u16* Pgb   = (u16*)(ws + OF_O1);   // 32MB, dead after k_attnw
  float* o1   = ws + OF_O1;
  float* o2   = ws + OF_O2;
  float* fv   = ws + OF_FV;
  float* gates = ws + OF_GATES;
  float* imps  = ws + OF_IMPS;
  int* cnt    = (int*)(ws + OF_CNT);
  int* basep  = (int*)(ws + OF_BASE);
  int* curs   = (int*)(ws + OF_CURS);
  float* lossws = ws + OF_LOSS;
  int* topi   = (int*)(ws + OF_TOPI);
  int* rowpos = (int*)(ws + OF_RPOS);
  int* rowlist= (int*)(ws + OF_RLIST);
  u16* Hbuf  = (u16*)(ws + OF_Q);    // MoE overlay on [OF_Q, OF_O1)
  float* YB  = ws + OF_PATCH;        // MoE overlay
  u16* XNB   = (u16*)(ws + OF_PATCH);// bf16 xn (XP dead post-pe-GEMM)
  u16* W1T   = (u16*)(ws + OF_O1);   // MoE overlay (after Pg dead)
  u16* W2T   = (u16*)(ws + OF_O2);

  float* out = (float*)d_out;
  float* out_logits = out;
  float* out_fv     = out + 16384;
  float* out_loss   = out + 32768;
  float* out_attnw  = out + 32769;

  // ---- dense weight prep ----
  k_wcvtd<<<dim3(20, 16), 256, 0, stream>>>(pe_w, peT, 588, 640);
  k_wcvtd<<<dim3(16, 16), 256, 0, stream>>>(wq, wqT, 512, 512);
  k_wcvtd<<<dim3(16, 16), 256, 0, stream>>>(wk, wkT, 512, 512);
  k_wcvtd<<<dim3(16, 16), 256, 0, stream>>>(wv, wvT, 512, 512);
  k_wcvtd<<<dim3(16, 16), 256, 0, stream>>>(wo, woT, 512, 512);

  k_patchify<<<20480, 256, 0, stream>>>(x, XP);
  k_bgemm<0><<<dim3(4, 64), 256, 0, stream>>>(XP, peT, pe_b, ebuf, nullptr, pos, 640);
  k_ln<<<8192, 256, 0, stream>>>(ebuf, xn, XNB, ln1g, ln1b);
  k_bgemm<1><<<dim3(4, 64), 256, 0, stream>>>(XNB, wqT, bq, nullptr, Q16, nullptr, 512);
  k_bgemm<1><<<dim3(4, 64), 256, 0, stream>>>(XNB, wkT, bk, nullptr, K16, nullptr, 512);
  k_bgemm<3><<<dim3(4, 64), 256, 0, stream>>>(XNB, wvT, bv, nullptr, VTb, nullptr, 512);
  k_fattn<<<dim3(4, 8, 32), 256, 0, stream>>>(Q16, K16, VTb, ctx16, Pgb);
  k_attnw<<<dim3(16, 32), 256, 0, stream>>>(Pgb, out_attnw);
  k_bgemm<2><<<dim3(4, 64), 256, 0, stream>>>(ctx16, woT, bo, ebuf, nullptr, nullptr, 512);

  const float* moe_in[2] = {ebuf, o1};
  float* moe_out[2] = {o1, o2};
  for (int mi = 0; mi < 2; mi++) {
    hipMemsetAsync(imps, 0, 64, stream);   // zero imps(32B) + cnt(32B)
    k_ln<<<8192, 256, 0, stream>>>(moe_in[mi], xn, XNB, lng[mi], lnb[mi]);
    // weight cvt AFTER LN: layer-2 must consume o1 before W1T overlay clobbers it
    k_wcvt<<<dim3(16, 64, 8), 256, 0, stream>>>(m_w1[mi], W1T, 512, 2048);
    k_wcvt<<<dim3(64, 16, 8), 256, 0, stream>>>(m_w2[mi], W2T, 2048, 512);
    k_router<<<256, 256, 0, stream>>>(xn, m_rw[mi], m_rb[mi], gates, topi, cnt, imps);
    k_scan<<<1, 64, 0, stream>>>(cnt, basep, curs);
    k_scatter<<<32, 256, 0, stream>>>(topi, basep, curs, rowlist, rowpos);
    k_loss<<<1, 64, 0, stream>>>(cnt, imps, lossws, out_loss, mi);
    k_mg1<<<dim3(16, 64, 8), 512, 0, stream>>>(XNB, W1T, m_b1[mi], Hbuf, rowlist, basep, cnt);
    k_mg2<<<dim3(4, 64, 8), 512, 0, stream>>>(Hbuf, W2T, m_b2[mi], YB, basep, cnt);
    k_combine<<<16384, 256, 0, stream>>>(YB, gates, rowpos, moe_out[mi]);
  }
  k_fv<<<64, 256, 0, stream>>>(o2, fv, out_fv);
  k_cls<<<64, 256, 0, stream>>>(fv, cls_w, cls_b, out_logits);
}